// Round 5
// baseline (665.339 us; speedup 1.0000x reference)
//
#include <hip/hip_runtime.h>
#include <cstdint>

// Problem constants
#define B_   4
#define S_   2048
#define D_   1024
#define H_   16
#define HD_  64
#define FF_  4096
#define MTOK 8192   // B_*S_

// may_alias: these type-pun LDS/global u16 buffers; without it TBAA treats
// short8-loads vs ushort-stores as no-alias and reorders them (round-2 NaN).
typedef short s16x8 __attribute__((ext_vector_type(8), may_alias));
typedef float f32x4 __attribute__((ext_vector_type(4)));
typedef unsigned short u16x4 __attribute__((ext_vector_type(4), may_alias));

// async global->LDS, 16B per lane, dest = uniform base + lane*16
#define GLD_LDS16(g, l)                                                  \
  __builtin_amdgcn_global_load_lds(                                      \
      (__attribute__((address_space(1))) void*)(g),                      \
      (__attribute__((address_space(3))) void*)(l), 16, 0, 0)

__device__ __forceinline__ unsigned short f2bf(float f) {
  unsigned u = __float_as_uint(f);
  unsigned r = 0x7fffu + ((u >> 16) & 1u);   // RNE
  return (unsigned short)((u + r) >> 16);
}

// ---------------- weight transpose + fp32->bf16 ----------------
__global__ __launch_bounds__(256) void k_transpose(const float* __restrict__ in,
                                                   unsigned short* __restrict__ out,
                                                   int R, int C) {
  __shared__ float tile[32][33];
  int tx = threadIdx.x, ty = threadIdx.y;             // 32 x 8
  int c0 = blockIdx.x * 32, r0 = blockIdx.y * 32;
#pragma unroll
  for (int j = 0; j < 4; ++j)
    tile[ty + j * 8][tx] = in[(size_t)(r0 + ty + j * 8) * C + (c0 + tx)];
  __syncthreads();
#pragma unroll
  for (int j = 0; j < 4; ++j)
    out[(size_t)(c0 + ty + j * 8) * R + (r0 + tx)] = f2bf(tile[tx][ty + j * 8]);
}

// ---------------- LayerNorm (D=1024, one block per row) ----------------
__global__ __launch_bounds__(256) void k_layernorm(const float* __restrict__ x,
                                                   const float* __restrict__ g,
                                                   const float* __restrict__ be,
                                                   unsigned short* __restrict__ out) {
  int row = blockIdx.x, t = threadIdx.x;
  const float4* xr = (const float4*)(x + (size_t)row * D_);
  float4 v = xr[t];
  float s = v.x + v.y + v.z + v.w;
  float q = v.x * v.x + v.y * v.y + v.z * v.z + v.w * v.w;
#pragma unroll
  for (int o = 1; o < 64; o <<= 1) { s += __shfl_xor(s, o); q += __shfl_xor(q, o); }
  __shared__ float red[8];
  int wid = t >> 6;
  if ((t & 63) == 0) { red[wid * 2] = s; red[wid * 2 + 1] = q; }
  __syncthreads();
  s = red[0] + red[2] + red[4] + red[6];
  q = red[1] + red[3] + red[5] + red[7];
  float mean = s * (1.0f / D_);
  float rstd = rsqrtf(q * (1.0f / D_) - mean * mean + 1e-5f);
  float4 gv = ((const float4*)g)[t];
  float4 bv = ((const float4*)be)[t];
  u16x4 o4;
  o4[0] = f2bf(gv.x * (v.x - mean) * rstd + bv.x);
  o4[1] = f2bf(gv.y * (v.y - mean) * rstd + bv.y);
  o4[2] = f2bf(gv.z * (v.z - mean) * rstd + bv.z);
  o4[3] = f2bf(gv.w * (v.w - mean) * rstd + bv.w);
  *(u16x4*)(out + (size_t)row * D_ + t * 4) = o4;
}

// ---------------- GEMM: C = A[M][K] * Bt[N][K]^T  (m97 structure) ----------------
// MODE 1: + bias, GELU(tanh) -> bf16 out
// MODE 2: + bias, + f32 residual -> f32 out
// MODE 3: fused QKV epilogue: col<1024 -> Q*0.125 (bf16), <2048 -> K (bf16),
//         else V written transposed per head: vbT[(b*16+h)*64+d][s]
// Grid flattened + bijective XCD swizzle (all grids have nwg%8==0).
template <int MODE>
__global__ __launch_bounds__(256) void k_gemm_bt(
    const unsigned short* __restrict__ A, const unsigned short* __restrict__ Bt,
    const float* __restrict__ bias, const float* __restrict__ resid,
    unsigned short* __restrict__ outb, float* __restrict__ outf,
    int M, int N, int K) {
  __shared__ __align__(16) unsigned short As[128 * 32];
  __shared__ __align__(16) unsigned short Bs[128 * 32];
  const int tid = threadIdx.x;
  const int wid = tid >> 6, lane = tid & 63;
  // XCD-aware swizzle: contiguous chunk of flattened ids per XCD (T1).
  const int nwg = gridDim.x * gridDim.y;
  const int id = blockIdx.y * gridDim.x + blockIdx.x;
  const int swz = (id & 7) * (nwg >> 3) + (id >> 3);
  const int m0 = (swz / gridDim.x) * 128, n0 = (swz % gridDim.x) * 128;
  const int wr = wid >> 1, wc = wid & 1;
  f32x4 acc[4][4];
#pragma unroll
  for (int m = 0; m < 4; ++m)
#pragma unroll
    for (int n = 0; n < 4; ++n) acc[m][n] = 0.0f;

  const unsigned short* aSrc[2];
  const unsigned short* bSrc[2];
  char* aDst[2];
  char* bDst[2];
#pragma unroll
  for (int i = 0; i < 2; ++i) {
    int chunk = (i * 4 + wid) * 64 + lane;   // 16B chunk id, 512 per 8KB tile
    int row = chunk >> 2, col = (chunk & 3) * 8;
    aSrc[i] = A + (size_t)(m0 + row) * K + col;
    bSrc[i] = Bt + (size_t)(n0 + row) * K + col;
    aDst[i] = (char*)As + (size_t)(i * 4 + wid) * 1024;
    bDst[i] = (char*)Bs + (size_t)(i * 4 + wid) * 1024;
  }
  const unsigned short* aRd = As + ((wr * 64 + (lane & 15)) * 32 + (lane >> 4) * 8);
  const unsigned short* bRd = Bs + ((wc * 64 + (lane & 15)) * 32 + (lane >> 4) * 8);

  for (int kt = 0; kt < K; kt += 32) {
    __syncthreads();                         // previous tile's compute done
#pragma unroll
    for (int i = 0; i < 2; ++i) {
      GLD_LDS16(aSrc[i] + kt, aDst[i]);
      GLD_LDS16(bSrc[i] + kt, bDst[i]);
    }
    __syncthreads();                         // vmcnt(0) drain + visibility
    s16x8 af[4], bfr[4];
#pragma unroll
    for (int m = 0; m < 4; ++m) af[m] = *(const s16x8*)(aRd + m * 16 * 32);
#pragma unroll
    for (int n = 0; n < 4; ++n) bfr[n] = *(const s16x8*)(bRd + n * 16 * 32);
#pragma unroll
    for (int m = 0; m < 4; ++m)
#pragma unroll
      for (int n = 0; n < 4; ++n)
        acc[m][n] = __builtin_amdgcn_mfma_f32_16x16x32_bf16(af[m], bfr[n], acc[m][n], 0, 0, 0);
  }

  const int colb = n0 + wc * 64 + (lane & 15);
  const int rowb = m0 + wr * 64 + ((lane >> 4) << 2);

  if (MODE == 3) {
    unsigned short* qout = outb;
    unsigned short* kout = outb + (size_t)MTOK * D_;
    unsigned short* vout = outb + 2 * (size_t)MTOK * D_;
    if (n0 < 1024) {
#pragma unroll
      for (int n = 0; n < 4; ++n) {
        int col = colb + n * 16;
#pragma unroll
        for (int m = 0; m < 4; ++m)
#pragma unroll
          for (int r = 0; r < 4; ++r)
            qout[(size_t)(rowb + m * 16 + r) * D_ + col] = f2bf(acc[m][n][r] * 0.125f);
      }
    } else if (n0 < 2048) {
#pragma unroll
      for (int n = 0; n < 4; ++n) {
        int col = colb + n * 16 - 1024;
#pragma unroll
        for (int m = 0; m < 4; ++m)
#pragma unroll
          for (int r = 0; r < 4; ++r)
            kout[(size_t)(rowb + m * 16 + r) * D_ + col] = f2bf(acc[m][n][r]);
      }
    } else {
      // V transposed: vout[(b*1024 + h*64 + d)][s],  (h*64+d) = col-2048
#pragma unroll
      for (int n = 0; n < 4; ++n) {
        int col2 = colb + n * 16 - 2048;
#pragma unroll
        for (int m = 0; m < 4; ++m) {
          int row0 = rowb + m * 16;            // token, 4-aligned; 4 consecutive s
          u16x4 pk;
#pragma unroll
          for (int r = 0; r < 4; ++r) pk[r] = f2bf(acc[m][n][r]);
          *(u16x4*)(vout + (size_t)((row0 >> 11) * 1024 + col2) * S_ + (row0 & 2047)) = pk;
        }
      }
    }
    return;
  }

#pragma unroll
  for (int n = 0; n < 4; ++n) {
    int col = colb + n * 16;
    float bv = bias[col];
#pragma unroll
    for (int m = 0; m < 4; ++m)
#pragma unroll
      for (int r = 0; r < 4; ++r) {
        int row = rowb + m * 16 + r;
        float val = acc[m][n][r] + bv;
        if (MODE == 1) {
          float u = 0.7978845608028654f * (val + 0.044715f * val * val * val);
          val = 0.5f * val * (1.0f + tanhf(u));
          outb[(size_t)row * N + col] = f2bf(val);
        }
        if (MODE == 2) {
          val += resid[(size_t)row * N + col];
          outf[(size_t)row * N + col] = val;
        }
      }
  }
}

// ---------------- causal flash attention (paired strips, reg-pipelined) ----------------
// Round-5 structure: software-pipelined loads so no global latency is exposed:
//   tile top:  issue V(t) loads (indep of K/P)        -> hidden under QK^T+softmax
//   post-QK^T: issue K(t+1) loads (double-buffered)   -> hidden under softmax+fence+PV
// lgkmcnt-only fence between P ds_writes and PV ds_reads (vmcnt loads span it).
// Even/odd unrolled K buffers keep all indexing static (rule 20).
// ~200 VGPR -> __launch_bounds__(256,2): 2 waves/SIMD, ILP carries the rest.
__device__ __forceinline__ void attn_tile_body(
    int t, int qtA, int qtB, int l16, int lg,
    const unsigned short* __restrict__ Kb, const unsigned short* __restrict__ Vt,
    unsigned short* __restrict__ psA, unsigned short* __restrict__ psB,
    int myrowA, int myrowB,
    const s16x8& qfA0, const s16x8& qfA1, const s16x8& qfB0, const s16x8& qfB1,
    s16x8 (&KC0)[4], s16x8 (&KC1)[4], s16x8 (&KN0)[4], s16x8 (&KN1)[4],
    f32x4 (&oA)[4], f32x4 (&oB)[4], float (&lsumA)[4], float (&lsumB)[4]) {
  const int kv0 = t * 64;
  const bool doA = (t <= qtA);
  const float L2E = 1.4426950408889634f;
  // ---- issue V(t) loads first (latency spans QK^T + softmax + fence) ----
  s16x8 vf[2][4];
#pragma unroll
  for (int ks = 0; ks < 2; ++ks)
#pragma unroll
    for (int n = 0; n < 4; ++n)
      vf[ks][n] = *(const s16x8*)(Vt + (size_t)(n * 16 + l16) * S_ + kv0 + ks * 32 + lg * 8);
  // ---- QK^T with current K regs ----
  f32x4 saA[4], saB[4];
  if (doA) {
#pragma unroll
    for (int n = 0; n < 4; ++n) {
      saA[n] = (f32x4)0.0f;
      saA[n] = __builtin_amdgcn_mfma_f32_16x16x32_bf16(qfA0, KC0[n], saA[n], 0, 0, 0);
      saA[n] = __builtin_amdgcn_mfma_f32_16x16x32_bf16(qfA1, KC1[n], saA[n], 0, 0, 0);
    }
  }
#pragma unroll
  for (int n = 0; n < 4; ++n) {
    saB[n] = (f32x4)0.0f;
    saB[n] = __builtin_amdgcn_mfma_f32_16x16x32_bf16(qfB0, KC0[n], saB[n], 0, 0, 0);
    saB[n] = __builtin_amdgcn_mfma_f32_16x16x32_bf16(qfB1, KC1[n], saB[n], 0, 0, 0);
  }
  // ---- prefetch K(t+1) into the alternate buffer (latency spans to next tile) ----
  if (t < qtB) {
#pragma unroll
    for (int n = 0; n < 4; ++n) {
      const unsigned short* kr = Kb + (size_t)(kv0 + 64 + n * 16 + l16) * D_ + lg * 8;
      KN0[n] = *(const s16x8*)kr;
      KN1[n] = *(const s16x8*)(kr + 32);
    }
  }
  // ---- softmax + P stores, strip A ----
  if (doA) {
    const bool mask = (t == qtA);
#pragma unroll
    for (int r = 0; r < 4; ++r)
#pragma unroll
      for (int n = 0; n < 4; ++n) {
        float pv = exp2f((saA[n][r] - 12.0f) * L2E);
        if (mask && (kv0 + n * 16 + l16) > (myrowA + r)) pv = 0.0f;
        lsumA[r] += pv;
        psA[(lg * 4 + r) * 72 + n * 16 + l16] = f2bf(pv);
      }
  }
  // ---- softmax + P stores, strip B ----
  {
    const bool mask = (t == qtB);
#pragma unroll
    for (int r = 0; r < 4; ++r)
#pragma unroll
      for (int n = 0; n < 4; ++n) {
        float pv = exp2f((saB[n][r] - 12.0f) * L2E);
        if (mask && (kv0 + n * 16 + l16) > (myrowB + r)) pv = 0.0f;
        lsumB[r] += pv;
        psB[(lg * 4 + r) * 72 + n * 16 + l16] = f2bf(pv);
      }
  }
  // Fence: P ds_writes complete before PV ds_reads (rule 18). lgkmcnt only --
  // the in-flight global loads (V(t), K(t+1)) are vmcnt and legally span it.
  __builtin_amdgcn_sched_barrier(0);
  asm volatile("s_waitcnt lgkmcnt(0)" ::: "memory");
  __builtin_amdgcn_sched_barrier(0);
  // ---- PV (V already in regs) ----
#pragma unroll
  for (int ks = 0; ks < 2; ++ks) {
    s16x8 paB = *(const s16x8*)(psB + l16 * 72 + ks * 32 + lg * 8);
    s16x8 paA;
    if (doA) paA = *(const s16x8*)(psA + l16 * 72 + ks * 32 + lg * 8);
#pragma unroll
    for (int n = 0; n < 4; ++n) {
      oB[n] = __builtin_amdgcn_mfma_f32_16x16x32_bf16(paB, vf[ks][n], oB[n], 0, 0, 0);
      if (doA) oA[n] = __builtin_amdgcn_mfma_f32_16x16x32_bf16(paA, vf[ks][n], oA[n], 0, 0, 0);
    }
  }
}

__global__ __launch_bounds__(256, 2) void k_attn(
    const unsigned short* __restrict__ qg, const unsigned short* __restrict__ kg,
    const unsigned short* __restrict__ vtg, unsigned short* __restrict__ ctx) {
  const int id = blockIdx.x;                 // 0..1023
  const int bh = (id & 7) + 8 * (id >> 7);   // head stays on one XCD (L2 locality)
  const int p  = (id >> 3) & 15;             // pair index
  const int qtA = p, qtB = 31 - p;           // (p+1)+(32-p)=33 tiles, all blocks equal
  const int tid = threadIdx.x, wid = tid >> 6, lane = tid & 63;
  const int l16 = lane & 15, lg = lane >> 4;
  __shared__ __align__(16) unsigned short Ps[4][2][16 * 72];   // [wave][strip]

  const size_t headoff = (size_t)(bh >> 4) * ((size_t)S_ * D_) + (size_t)(bh & 15) * HD_;
  const unsigned short* Kb = kg + headoff;
  const unsigned short* Vt = vtg + (size_t)bh * ((size_t)HD_ * S_);

  const int qrowA = qtA * 64 + wid * 16 + l16;
  const int qrowB = qtB * 64 + wid * 16 + l16;
  s16x8 qfA0 = *(const s16x8*)(qg + headoff + (size_t)qrowA * D_ + lg * 8);
  s16x8 qfA1 = *(const s16x8*)(qg + headoff + (size_t)qrowA * D_ + 32 + lg * 8);
  s16x8 qfB0 = *(const s16x8*)(qg + headoff + (size_t)qrowB * D_ + lg * 8);
  s16x8 qfB1 = *(const s16x8*)(qg + headoff + (size_t)qrowB * D_ + 32 + lg * 8);

  f32x4 oA[4], oB[4];
#pragma unroll
  for (int n = 0; n < 4; ++n) { oA[n] = (f32x4)0.0f; oB[n] = (f32x4)0.0f; }
  float lsumA[4] = {0.f, 0.f, 0.f, 0.f};
  float lsumB[4] = {0.f, 0.f, 0.f, 0.f};
  unsigned short* psA = &Ps[wid][0][0];
  unsigned short* psB = &Ps[wid][1][0];
  const int myrowA = qtA * 64 + wid * 16 + lg * 4;
  const int myrowB = qtB * 64 + wid * 16 + lg * 4;

  // K double-buffer; prologue load of tile 0
  s16x8 kA0[4], kA1[4], kB0[4], kB1[4];
#pragma unroll
  for (int n = 0; n < 4; ++n) {
    const unsigned short* kr = Kb + (size_t)(n * 16 + l16) * D_ + lg * 8;
    kA0[n] = *(const s16x8*)kr;
    kA1[n] = *(const s16x8*)(kr + 32);
  }

  for (int t = 0; t <= qtB; ++t) {
    if ((t & 1) == 0)
      attn_tile_body(t, qtA, qtB, l16, lg, Kb, Vt, psA, psB, myrowA, myrowB,
                     qfA0, qfA1, qfB0, qfB1, kA0, kA1, kB0, kB1,
                     oA, oB, lsumA, lsumB);
    else
      attn_tile_body(t, qtA, qtB, l16, lg, Kb, Vt, psA, psB, myrowA, myrowB,
                     qfA0, qfA1, qfB0, qfB1, kB0, kB1, kA0, kA1,
                     oA, oB, lsumA, lsumB);
  }

  // ---- finalize both strips ----
#pragma unroll
  for (int r = 0; r < 4; ++r) {
    float la = lsumA[r], lb = lsumB[r];
    la += __shfl_xor(la, 1); lb += __shfl_xor(lb, 1);
    la += __shfl_xor(la, 2); lb += __shfl_xor(lb, 2);
    la += __shfl_xor(la, 4); lb += __shfl_xor(lb, 4);
    la += __shfl_xor(la, 8); lb += __shfl_xor(lb, 8);
    float ia = 1.0f / la, ib = 1.0f / lb;
#pragma unroll
    for (int n = 0; n < 4; ++n) {
      ctx[headoff + (size_t)(myrowA + r) * D_ + n * 16 + l16] = f2bf(oA[n][r] * ia);
      ctx[headoff + (size_t)(myrowB + r) * D_ + n * 16 + l16] = f2bf(oB[n][r] * ib);
    }
  }
}

// ---------------- launch ----------------
extern "C" void kernel_launch(void* const* d_in, const int* in_sizes, int n_in,
                              void* d_out, int out_size, void* d_ws, size_t ws_size,
                              hipStream_t stream) {
  (void)in_sizes; (void)n_in; (void)out_size; (void)ws_size;
  const float* x   = (const float*)d_in[0];
  const float* Wq  = (const float*)d_in[1];
  const float* Wk  = (const float*)d_in[2];
  const float* Wv  = (const float*)d_in[3];
  const float* Wo  = (const float*)d_in[4];
  const float* bo  = (const float*)d_in[5];
  const float* W1  = (const float*)d_in[6];
  const float* b1  = (const float*)d_in[7];
  const float* W2  = (const float*)d_in[8];
  const float* b2  = (const float*)d_in[9];
  const float* g1  = (const float*)d_in[10];
  const float* be1 = (const float*)d_in[11];
  const float* g2  = (const float*)d_in[12];
  const float* be2 = (const float*)d_in[13];
  float* out = (float*)d_out;

  // workspace layout (136 MB):
  //  0MB  wqkvT (bf16 [3072][1024], 6MB)
  //  6MB  woT   (bf16 [1024][1024], 2MB)
  //  8MB  w1T   (bf16 [4096][1024], 8MB)
  // 16MB  w2T   (bf16 [1024][4096], 8MB)
  // 24MB  hb    (bf16 [8192][1024], 16MB)
  // 40MB  x2    (f32  [8192][1024], 32MB)
  // 72MB  qb (16) | 88MB kb (16) | 104MB vbT (16) | 120MB cxb (16)
  //       act (64MB) aliases 72..136MB after attention phase
  char* w = (char*)d_ws;
  const size_t MB = 1ull << 20;
  unsigned short* wqkvT = (unsigned short*)(w + 0 * MB);
  unsigned short* woT   = (unsigned short*)(w + 6 * MB);
  unsigned short* w1T   = (unsigned short*)(w + 8 * MB);
  unsigned short* w2T   = (unsigned short*)(w + 16 * MB);
  unsigned short* hb    = (unsigned short*)(w + 24 * MB);
  float*          x2    = (float*)(w + 40 * MB);
  unsigned short* qkv   = (unsigned short*)(w + 72 * MB);   // qb | kb | vbT
  unsigned short* qb    = qkv;
  unsigned short* kb    = qkv + (size_t)MTOK * D_;
  unsigned short* vbT   = qkv + 2 * (size_t)MTOK * D_;
  unsigned short* cxb   = (unsigned short*)(w + 120 * MB);
  unsigned short* act   = (unsigned short*)(w + 72 * MB);   // aliases qkv region

  dim3 tb(32, 8);
  k_transpose<<<dim3(32, 32), tb, 0, stream>>>(Wq, wqkvT, 1024, 1024);
  k_transpose<<<dim3(32, 32), tb, 0, stream>>>(Wk, wqkvT + 1024 * 1024, 1024, 1024);
  k_transpose<<<dim3(32, 32), tb, 0, stream>>>(Wv, wqkvT + 2048 * 1024, 1024, 1024);
  k_transpose<<<dim3(32, 32), tb, 0, stream>>>(Wo, woT, 1024, 1024);
  k_transpose<<<dim3(128, 32), tb, 0, stream>>>(W1, w1T, 1024, 4096);
  k_transpose<<<dim3(32, 128), tb, 0, stream>>>(W2, w2T, 4096, 1024);

  k_layernorm<<<MTOK, 256, 0, stream>>>(x, g1, be1, hb);

  k_gemm_bt<3><<<dim3(24, 64), 256, 0, stream>>>(hb, wqkvT, nullptr, nullptr, qkv, nullptr, MTOK, 3072, 1024);

  k_attn<<<1024, 256, 0, stream>>>(qb, kb, vbT, cxb);

  k_gemm_bt<2><<<dim3(8, 64), 256, 0, stream>>>(cxb, woT, bo, x, nullptr, x2, MTOK, 1024, 1024);

  k_layernorm<<<MTOK, 256, 0, stream>>>(x2, g2, be2, hb);

  k_gemm_bt<1><<<dim3(32, 64), 256, 0, stream>>>(hb, w1T, b1, nullptr, act, nullptr, MTOK, 4096, 1024);
  k_gemm_bt<2><<<dim3(8, 64), 256, 0, stream>>>(act, w2T, b2, x2, nullptr, out, MTOK, 1024, 4096);
}

// Round 6
// 469.074 us; speedup vs baseline: 1.4184x; 1.4184x over previous
//
#include <hip/hip_runtime.h>
#include <cstdint>

// Problem constants
#define B_   4
#define S_   2048
#define D_   1024
#define H_   16
#define HD_  64
#define FF_  4096
#define MTOK 8192   // B_*S_

// may_alias: these type-pun LDS/global u16 buffers; without it TBAA treats
// short8-loads vs ushort-stores as no-alias and reorders them (round-2 NaN).
typedef short s16x8 __attribute__((ext_vector_type(8), may_alias));
typedef float f32x4 __attribute__((ext_vector_type(4)));
typedef unsigned short u16x4 __attribute__((ext_vector_type(4), may_alias));

// async global->LDS, 16B per lane, dest = uniform base + lane*16
#define GLD_LDS16(g, l)                                                  \
  __builtin_amdgcn_global_load_lds(                                      \
      (__attribute__((address_space(1))) void*)(g),                      \
      (__attribute__((address_space(3))) void*)(l), 16, 0, 0)

__device__ __forceinline__ unsigned short f2bf(float f) {
  unsigned u = __float_as_uint(f);
  unsigned r = 0x7fffu + ((u >> 16) & 1u);   // RNE
  return (unsigned short)((u + r) >> 16);
}

// ---------------- weight transpose + fp32->bf16 ----------------
__global__ __launch_bounds__(256) void k_transpose(const float* __restrict__ in,
                                                   unsigned short* __restrict__ out,
                                                   int R, int C) {
  __shared__ float tile[32][33];
  int tx = threadIdx.x, ty = threadIdx.y;             // 32 x 8
  int c0 = blockIdx.x * 32, r0 = blockIdx.y * 32;
#pragma unroll
  for (int j = 0; j < 4; ++j)
    tile[ty + j * 8][tx] = in[(size_t)(r0 + ty + j * 8) * C + (c0 + tx)];
  __syncthreads();
#pragma unroll
  for (int j = 0; j < 4; ++j)
    out[(size_t)(c0 + ty + j * 8) * R + (r0 + tx)] = f2bf(tile[tx][ty + j * 8]);
}

// ---------------- LayerNorm (D=1024, one block per row) ----------------
__global__ __launch_bounds__(256) void k_layernorm(const float* __restrict__ x,
                                                   const float* __restrict__ g,
                                                   const float* __restrict__ be,
                                                   unsigned short* __restrict__ out) {
  int row = blockIdx.x, t = threadIdx.x;
  const float4* xr = (const float4*)(x + (size_t)row * D_);
  float4 v = xr[t];
  float s = v.x + v.y + v.z + v.w;
  float q = v.x * v.x + v.y * v.y + v.z * v.z + v.w * v.w;
#pragma unroll
  for (int o = 1; o < 64; o <<= 1) { s += __shfl_xor(s, o); q += __shfl_xor(q, o); }
  __shared__ float red[8];
  int wid = t >> 6;
  if ((t & 63) == 0) { red[wid * 2] = s; red[wid * 2 + 1] = q; }
  __syncthreads();
  s = red[0] + red[2] + red[4] + red[6];
  q = red[1] + red[3] + red[5] + red[7];
  float mean = s * (1.0f / D_);
  float rstd = rsqrtf(q * (1.0f / D_) - mean * mean + 1e-5f);
  float4 gv = ((const float4*)g)[t];
  float4 bv = ((const float4*)be)[t];
  u16x4 o4;
  o4[0] = f2bf(gv.x * (v.x - mean) * rstd + bv.x);
  o4[1] = f2bf(gv.y * (v.y - mean) * rstd + bv.y);
  o4[2] = f2bf(gv.z * (v.z - mean) * rstd + bv.z);
  o4[3] = f2bf(gv.w * (v.w - mean) * rstd + bv.w);
  *(u16x4*)(out + (size_t)row * D_ + t * 4) = o4;
}

// ---------------- GEMM: C = A[M][K] * Bt[N][K]^T  (m97 structure) ----------------
// MODE 1: + bias, GELU(tanh) -> bf16 out
// MODE 2: + bias, + f32 residual -> f32 out
// MODE 3: fused QKV epilogue: col<1024 -> Q*0.125 (bf16), <2048 -> K (bf16),
//         else V written transposed per head: vbT[(b*16+h)*64+d][s]
// Grid flattened + bijective XCD swizzle (all grids have nwg%8==0).
template <int MODE>
__global__ __launch_bounds__(256) void k_gemm_bt(
    const unsigned short* __restrict__ A, const unsigned short* __restrict__ Bt,
    const float* __restrict__ bias, const float* __restrict__ resid,
    unsigned short* __restrict__ outb, float* __restrict__ outf,
    int M, int N, int K) {
  __shared__ __align__(16) unsigned short As[128 * 32];
  __shared__ __align__(16) unsigned short Bs[128 * 32];
  const int tid = threadIdx.x;
  const int wid = tid >> 6, lane = tid & 63;
  // XCD-aware swizzle: contiguous chunk of flattened ids per XCD (T1).
  const int nwg = gridDim.x * gridDim.y;
  const int id = blockIdx.y * gridDim.x + blockIdx.x;
  const int swz = (id & 7) * (nwg >> 3) + (id >> 3);
  const int m0 = (swz / gridDim.x) * 128, n0 = (swz % gridDim.x) * 128;
  const int wr = wid >> 1, wc = wid & 1;
  f32x4 acc[4][4];
#pragma unroll
  for (int m = 0; m < 4; ++m)
#pragma unroll
    for (int n = 0; n < 4; ++n) acc[m][n] = 0.0f;

  const unsigned short* aSrc[2];
  const unsigned short* bSrc[2];
  char* aDst[2];
  char* bDst[2];
#pragma unroll
  for (int i = 0; i < 2; ++i) {
    int chunk = (i * 4 + wid) * 64 + lane;   // 16B chunk id, 512 per 8KB tile
    int row = chunk >> 2, col = (chunk & 3) * 8;
    aSrc[i] = A + (size_t)(m0 + row) * K + col;
    bSrc[i] = Bt + (size_t)(n0 + row) * K + col;
    aDst[i] = (char*)As + (size_t)(i * 4 + wid) * 1024;
    bDst[i] = (char*)Bs + (size_t)(i * 4 + wid) * 1024;
  }
  const unsigned short* aRd = As + ((wr * 64 + (lane & 15)) * 32 + (lane >> 4) * 8);
  const unsigned short* bRd = Bs + ((wc * 64 + (lane & 15)) * 32 + (lane >> 4) * 8);

  for (int kt = 0; kt < K; kt += 32) {
    __syncthreads();                         // previous tile's compute done
#pragma unroll
    for (int i = 0; i < 2; ++i) {
      GLD_LDS16(aSrc[i] + kt, aDst[i]);
      GLD_LDS16(bSrc[i] + kt, bDst[i]);
    }
    __syncthreads();                         // vmcnt(0) drain + visibility
    s16x8 af[4], bfr[4];
#pragma unroll
    for (int m = 0; m < 4; ++m) af[m] = *(const s16x8*)(aRd + m * 16 * 32);
#pragma unroll
    for (int n = 0; n < 4; ++n) bfr[n] = *(const s16x8*)(bRd + n * 16 * 32);
#pragma unroll
    for (int m = 0; m < 4; ++m)
#pragma unroll
      for (int n = 0; n < 4; ++n)
        acc[m][n] = __builtin_amdgcn_mfma_f32_16x16x32_bf16(af[m], bfr[n], acc[m][n], 0, 0, 0);
  }

  const int colb = n0 + wc * 64 + (lane & 15);
  const int rowb = m0 + wr * 64 + ((lane >> 4) << 2);

  if (MODE == 3) {
    unsigned short* qout = outb;
    unsigned short* kout = outb + (size_t)MTOK * D_;
    unsigned short* vout = outb + 2 * (size_t)MTOK * D_;
    if (n0 < 1024) {
#pragma unroll
      for (int n = 0; n < 4; ++n) {
        int col = colb + n * 16;
#pragma unroll
        for (int m = 0; m < 4; ++m)
#pragma unroll
          for (int r = 0; r < 4; ++r)
            qout[(size_t)(rowb + m * 16 + r) * D_ + col] = f2bf(acc[m][n][r] * 0.125f);
      }
    } else if (n0 < 2048) {
#pragma unroll
      for (int n = 0; n < 4; ++n) {
        int col = colb + n * 16 - 1024;
#pragma unroll
        for (int m = 0; m < 4; ++m)
#pragma unroll
          for (int r = 0; r < 4; ++r)
            kout[(size_t)(rowb + m * 16 + r) * D_ + col] = f2bf(acc[m][n][r]);
      }
    } else {
      // V transposed: vout[(b*1024 + h*64 + d)][s],  (h*64+d) = col-2048
#pragma unroll
      for (int n = 0; n < 4; ++n) {
        int col2 = colb + n * 16 - 2048;
#pragma unroll
        for (int m = 0; m < 4; ++m) {
          int row0 = rowb + m * 16;            // token, 4-aligned; 4 consecutive s
          u16x4 pk;
#pragma unroll
          for (int r = 0; r < 4; ++r) pk[r] = f2bf(acc[m][n][r]);
          *(u16x4*)(vout + (size_t)((row0 >> 11) * 1024 + col2) * S_ + (row0 & 2047)) = pk;
        }
      }
    }
    return;
  }

#pragma unroll
  for (int n = 0; n < 4; ++n) {
    int col = colb + n * 16;
    float bv = bias[col];
#pragma unroll
    for (int m = 0; m < 4; ++m)
#pragma unroll
      for (int r = 0; r < 4; ++r) {
        int row = rowb + m * 16 + r;
        float val = acc[m][n][r] + bv;
        if (MODE == 1) {
          float u = 0.7978845608028654f * (val + 0.044715f * val * val * val);
          val = 0.5f * val * (1.0f + tanhf(u));
          outb[(size_t)row * N + col] = f2bf(val);
        }
        if (MODE == 2) {
          val += resid[(size_t)row * N + col];
          outf[(size_t)row * N + col] = val;
        }
      }
  }
}

// ---------------- causal flash attention (paired strips, LDS-DMA pipelined) ----------------
// Round-6: K and V tiles staged in double-buffered LDS via global_load_lds
// (zero VGPR cost -- round-5's register pipeline spilled 254MB to scratch).
// DMA for tile t+1 issued BEFORE computing tile t; the single end-of-tile
// __syncthreads (compiler drains vmcnt before s_barrier) lands ~500 compute
// cycles after issue -> latency hidden. XOR-swizzled staging (rule 21:
// pre-swizzled global source + swizzled LDS read = 2-way-free fragments).
// Paired strips (qtA=p, qtB=31-p, 33 tiles/block) keep per-CU balance;
// fixed-max softmax p=exp2((s-12)*log2e); lgkmcnt fence for P write->read.
__global__ __launch_bounds__(256, 3) void k_attn(
    const unsigned short* __restrict__ qg, const unsigned short* __restrict__ kg,
    const unsigned short* __restrict__ vtg, unsigned short* __restrict__ ctx) {
  const int id = blockIdx.x;                 // 0..1023
  const int bh = (id & 7) + 8 * (id >> 7);   // head stays on one XCD (L2 locality)
  const int p  = (id >> 3) & 15;             // pair index
  const int qtA = p, qtB = 31 - p;           // (p+1)+(32-p)=33 tiles, all blocks equal
  const int tid = threadIdx.x, wid = tid >> 6, lane = tid & 63;
  const int l16 = lane & 15, lg = lane >> 4;
  __shared__ __align__(16) unsigned short Ks[2][64 * 64];      // 16 KB dbuf
  __shared__ __align__(16) unsigned short Vs[2][64 * 64];      // 16 KB dbuf
  __shared__ __align__(16) unsigned short Ps[4][2][16 * 72];   // 18 KB [wave][strip]

  const size_t headoff = (size_t)(bh >> 4) * ((size_t)S_ * D_) + (size_t)(bh & 15) * HD_;
  const unsigned short* Kb = kg + headoff;
  const unsigned short* Vt = vtg + (size_t)bh * ((size_t)HD_ * S_);

  const int qrowA = qtA * 64 + wid * 16 + l16;
  const int qrowB = qtB * 64 + wid * 16 + l16;
  s16x8 qfA0 = *(const s16x8*)(qg + headoff + (size_t)qrowA * D_ + lg * 8);
  s16x8 qfA1 = *(const s16x8*)(qg + headoff + (size_t)qrowA * D_ + 32 + lg * 8);
  s16x8 qfB0 = *(const s16x8*)(qg + headoff + (size_t)qrowB * D_ + lg * 8);
  s16x8 qfB1 = *(const s16x8*)(qg + headoff + (size_t)qrowB * D_ + 32 + lg * 8);

  f32x4 oA[4], oB[4];
#pragma unroll
  for (int n = 0; n < 4; ++n) { oA[n] = (f32x4)0.0f; oB[n] = (f32x4)0.0f; }
  float lsumA[4] = {0.f, 0.f, 0.f, 0.f};
  float lsumB[4] = {0.f, 0.f, 0.f, 0.f};
  unsigned short* psA = &Ps[wid][0][0];
  unsigned short* psB = &Ps[wid][1][0];
  const int myrowA = qtA * 64 + wid * 16 + lg * 4;
  const int myrowB = qtB * 64 + wid * 16 + lg * 4;
  const float L2E = 1.4426950408889634f;

  // Staging addresses: 512 16B-chunks per 8KB tile; 2 K-chunks + 2 V-chunks
  // per thread. Source column pre-swizzled by row (rule 21).
  const unsigned short* kSrc[2];
  const unsigned short* vSrc[2];
  int dstOff[2];
#pragma unroll
  for (int i = 0; i < 2; ++i) {
    int chunk = (i * 4 + wid) * 64 + lane;
    int row = chunk >> 3, pc = chunk & 7;
    int scol = (pc ^ (row & 7)) * 8;
    kSrc[i] = Kb + (size_t)row * D_ + scol;   // + kv0*D_ per tile
    vSrc[i] = Vt + (size_t)row * S_ + scol;   // + kv0 per tile
    dstOff[i] = (i * 4 + wid) * 1024;         // bytes
  }

  // ---- prologue: stage tile 0 into buf 0 ----
#pragma unroll
  for (int i = 0; i < 2; ++i) {
    GLD_LDS16(kSrc[i], (char*)Ks[0] + dstOff[i]);
    GLD_LDS16(vSrc[i], (char*)Vs[0] + dstOff[i]);
  }
  __syncthreads();                            // vmcnt(0) drain + visibility

  for (int t = 0; t <= qtB; ++t) {
    const int cur = t & 1;
    const int kv0 = t * 64;
    const bool doA = (t <= qtA);
    // ---- issue DMA for tile t+1 into the other buffer (latency spans compute) ----
    if (t < qtB) {
      const int kvn = kv0 + 64;
#pragma unroll
      for (int i = 0; i < 2; ++i) {
        GLD_LDS16(kSrc[i] + (size_t)kvn * D_, (char*)Ks[cur ^ 1] + dstOff[i]);
        GLD_LDS16(vSrc[i] + kvn, (char*)Vs[cur ^ 1] + dstOff[i]);
      }
    }
    const unsigned short* Kc = Ks[cur];
    const unsigned short* Vc = Vs[cur];
    // ---- K fragments (shared by both strips), swizzled read ----
    s16x8 kf0[4], kf1[4];
#pragma unroll
    for (int n = 0; n < 4; ++n) {
      int srow = n * 16 + l16, sw = srow & 7;
      kf0[n] = *(const s16x8*)(Kc + srow * 64 + (lg ^ sw) * 8);
      kf1[n] = *(const s16x8*)(Kc + srow * 64 + ((4 + lg) ^ sw) * 8);
    }
    // ---- QK^T ----
    f32x4 saA[4], saB[4];
    if (doA) {
#pragma unroll
      for (int n = 0; n < 4; ++n) {
        saA[n] = (f32x4)0.0f;
        saA[n] = __builtin_amdgcn_mfma_f32_16x16x32_bf16(qfA0, kf0[n], saA[n], 0, 0, 0);
        saA[n] = __builtin_amdgcn_mfma_f32_16x16x32_bf16(qfA1, kf1[n], saA[n], 0, 0, 0);
      }
    }
#pragma unroll
    for (int n = 0; n < 4; ++n) {
      saB[n] = (f32x4)0.0f;
      saB[n] = __builtin_amdgcn_mfma_f32_16x16x32_bf16(qfB0, kf0[n], saB[n], 0, 0, 0);
      saB[n] = __builtin_amdgcn_mfma_f32_16x16x32_bf16(qfB1, kf1[n], saB[n], 0, 0, 0);
    }
    // ---- softmax + P stores ----
    if (doA) {
      const bool mask = (t == qtA);
#pragma unroll
      for (int r = 0; r < 4; ++r)
#pragma unroll
        for (int n = 0; n < 4; ++n) {
          float pv = exp2f((saA[n][r] - 12.0f) * L2E);
          if (mask && (kv0 + n * 16 + l16) > (myrowA + r)) pv = 0.0f;
          lsumA[r] += pv;
          psA[(lg * 4 + r) * 72 + n * 16 + l16] = f2bf(pv);
        }
    }
    {
      const bool mask = (t == qtB);
#pragma unroll
      for (int r = 0; r < 4; ++r)
#pragma unroll
        for (int n = 0; n < 4; ++n) {
          float pv = exp2f((saB[n][r] - 12.0f) * L2E);
          if (mask && (kv0 + n * 16 + l16) > (myrowB + r)) pv = 0.0f;
          lsumB[r] += pv;
          psB[(lg * 4 + r) * 72 + n * 16 + l16] = f2bf(pv);
        }
    }
    // ---- V fragments (issued before fence; drained by it) ----
    s16x8 vf0[4], vf1[4];
#pragma unroll
    for (int n = 0; n < 4; ++n) {
      int srow = n * 16 + l16, sw = srow & 7;
      vf0[n] = *(const s16x8*)(Vc + srow * 64 + (lg ^ sw) * 8);
      vf1[n] = *(const s16x8*)(Vc + srow * 64 + ((4 + lg) ^ sw) * 8);
    }
    // Fence: P ds_writes (and vf ds_reads) complete before PV (rule 18).
    __builtin_amdgcn_sched_barrier(0);
    asm volatile("s_waitcnt lgkmcnt(0)" ::: "memory");
    __builtin_amdgcn_sched_barrier(0);
    // ---- PV ----
    {
      s16x8 paB0 = *(const s16x8*)(psB + l16 * 72 + lg * 8);
      s16x8 paB1 = *(const s16x8*)(psB + l16 * 72 + 32 + lg * 8);
#pragma unroll
      for (int n = 0; n < 4; ++n) {
        oB[n] = __builtin_amdgcn_mfma_f32_16x16x32_bf16(paB0, vf0[n], oB[n], 0, 0, 0);
        oB[n] = __builtin_amdgcn_mfma_f32_16x16x32_bf16(paB1, vf1[n], oB[n], 0, 0, 0);
      }
      if (doA) {
        s16x8 paA0 = *(const s16x8*)(psA + l16 * 72 + lg * 8);
        s16x8 paA1 = *(const s16x8*)(psA + l16 * 72 + 32 + lg * 8);
#pragma unroll
        for (int n = 0; n < 4; ++n) {
          oA[n] = __builtin_amdgcn_mfma_f32_16x16x32_bf16(paA0, vf0[n], oA[n], 0, 0, 0);
          oA[n] = __builtin_amdgcn_mfma_f32_16x16x32_bf16(paA1, vf1[n], oA[n], 0, 0, 0);
        }
      }
    }
    // End-of-tile barrier: (a) drains the t+1 DMAs (vmcnt(0) before s_barrier),
    // (b) all waves done reading buf[cur] before anyone stages over it next iter.
    __syncthreads();
  }

  // ---- finalize both strips ----
#pragma unroll
  for (int r = 0; r < 4; ++r) {
    float la = lsumA[r], lb = lsumB[r];
    la += __shfl_xor(la, 1); lb += __shfl_xor(lb, 1);
    la += __shfl_xor(la, 2); lb += __shfl_xor(lb, 2);
    la += __shfl_xor(la, 4); lb += __shfl_xor(lb, 4);
    la += __shfl_xor(la, 8); lb += __shfl_xor(lb, 8);
    float ia = 1.0f / la, ib = 1.0f / lb;
#pragma unroll
    for (int n = 0; n < 4; ++n) {
      ctx[headoff + (size_t)(myrowA + r) * D_ + n * 16 + l16] = f2bf(oA[n][r] * ia);
      ctx[headoff + (size_t)(myrowB + r) * D_ + n * 16 + l16] = f2bf(oB[n][r] * ib);
    }
  }
}

// ---------------- launch ----------------
extern "C" void kernel_launch(void* const* d_in, const int* in_sizes, int n_in,
                              void* d_out, int out_size, void* d_ws, size_t ws_size,
                              hipStream_t stream) {
  (void)in_sizes; (void)n_in; (void)out_size; (void)ws_size;
  const float* x   = (const float*)d_in[0];
  const float* Wq  = (const float*)d_in[1];
  const float* Wk  = (const float*)d_in[2];
  const float* Wv  = (const float*)d_in[3];
  const float* Wo  = (const float*)d_in[4];
  const float* bo  = (const float*)d_in[5];
  const float* W1  = (const float*)d_in[6];
  const float* b1  = (const float*)d_in[7];
  const float* W2  = (const float*)d_in[8];
  const float* b2  = (const float*)d_in[9];
  const float* g1  = (const float*)d_in[10];
  const float* be1 = (const float*)d_in[11];
  const float* g2  = (const float*)d_in[12];
  const float* be2 = (const float*)d_in[13];
  float* out = (float*)d_out;

  // workspace layout (136 MB):
  //  0MB  wqkvT (bf16 [3072][1024], 6MB)
  //  6MB  woT   (bf16 [1024][1024], 2MB)
  //  8MB  w1T   (bf16 [4096][1024], 8MB)
  // 16MB  w2T   (bf16 [1024][4096], 8MB)
  // 24MB  hb    (bf16 [8192][1024], 16MB)
  // 40MB  x2    (f32  [8192][1024], 32MB)
  // 72MB  qb (16) | 88MB kb (16) | 104MB vbT (16) | 120MB cxb (16)
  //       act (64MB) aliases 72..136MB after attention phase
  char* w = (char*)d_ws;
  const size_t MB = 1ull << 20;
  unsigned short* wqkvT = (unsigned short*)(w + 0 * MB);
  unsigned short* woT   = (unsigned short*)(w + 6 * MB);
  unsigned short* w1T   = (unsigned short*)(w + 8 * MB);
  unsigned short* w2T   = (unsigned short*)(w + 16 * MB);
  unsigned short* hb    = (unsigned short*)(w + 24 * MB);
  float*          x2    = (float*)(w + 40 * MB);
  unsigned short* qkv   = (unsigned short*)(w + 72 * MB);   // qb | kb | vbT
  unsigned short* qb    = qkv;
  unsigned short* kb    = qkv + (size_t)MTOK * D_;
  unsigned short* vbT   = qkv + 2 * (size_t)MTOK * D_;
  unsigned short* cxb   = (unsigned short*)(w + 120 * MB);
  unsigned short* act   = (unsigned short*)(w + 72 * MB);   // aliases qkv region

  dim3 tb(32, 8);
  k_transpose<<<dim3(32, 32), tb, 0, stream>>>(Wq, wqkvT, 1024, 1024);
  k_transpose<<<dim3(32, 32), tb, 0, stream>>>(Wk, wqkvT + 1024 * 1024, 1024, 1024);
  k_transpose<<<dim3(32, 32), tb, 0, stream>>>(Wv, wqkvT + 2048 * 1024, 1024, 1024);
  k_transpose<<<dim3(32, 32), tb, 0, stream>>>(Wo, woT, 1024, 1024);
  k_transpose<<<dim3(128, 32), tb, 0, stream>>>(W1, w1T, 1024, 4096);
  k_transpose<<<dim3(32, 128), tb, 0, stream>>>(W2, w2T, 4096, 1024);

  k_layernorm<<<MTOK, 256, 0, stream>>>(x, g1, be1, hb);

  k_gemm_bt<3><<<dim3(24, 64), 256, 0, stream>>>(hb, wqkvT, nullptr, nullptr, qkv, nullptr, MTOK, 3072, 1024);

  k_attn<<<1024, 256, 0, stream>>>(qb, kb, vbT, cxb);

  k_gemm_bt<2><<<dim3(8, 64), 256, 0, stream>>>(cxb, woT, bo, x, nullptr, x2, MTOK, 1024, 1024);

  k_layernorm<<<MTOK, 256, 0, stream>>>(x2, g2, be2, hb);

  k_gemm_bt<1><<<dim3(32, 64), 256, 0, stream>>>(hb, w1T, b1, nullptr, act, nullptr, MTOK, 4096, 1024);
  k_gemm_bt<2><<<dim3(8, 64), 256, 0, stream>>>(act, w2T, b2, x2, nullptr, out, MTOK, 1024, 4096);
}